// Round 4
// baseline (480.767 us; speedup 1.0000x reference)
//
#include <hip/hip_runtime.h>
#include <cstdint>
#include <cstddef>

#define N_NODES 65536
#define N_EDGES 1048576
#define E_TOT   (N_EDGES + N_NODES)
#define CAP     5120   // bucket region capacity (mean 4096, +16 sigma)

using short8  = __attribute__((ext_vector_type(8))) short;
using floatx4 = __attribute__((ext_vector_type(4))) float;
using half8   = __attribute__((ext_vector_type(8))) _Float16;
using half4   = __attribute__((ext_vector_type(4))) _Float16;
typedef unsigned short ushort_t;

// split fp32 -> bf16 hi (RTN) + bf16 lo (trunc of residual)
__device__ inline void split_bf16(float a, short& hi, short& lo) {
    unsigned u  = __float_as_uint(a);
    unsigned hr = (u + 0x7fffu + ((u >> 16) & 1u)) >> 16;
    float    hf = __uint_as_float(hr << 16);
    hi = (short)hr;
    float    lf = a - hf;
    lo = (short)(__float_as_uint(lf) >> 16);
}

// ---------------- preprocessing: bucket counting sort ----------------

__global__ __launch_bounds__(1024) void k_bucket(const int* __restrict__ src, const int* __restrict__ dst,
                                                 int* __restrict__ gcur, unsigned* __restrict__ pk) {
    __shared__ int cnt[256];
    __shared__ int cur[256];
    int tid = threadIdx.x;
    if (tid < 256) cnt[tid] = 0;
    __syncthreads();
    int base = blockIdx.x * 4096;
    #pragma unroll
    for (int j = 0; j < 4; ++j) {
        int d = __builtin_nontemporal_load(&dst[base + j * 1024 + tid]);
        atomicAdd(&cnt[d >> 8], 1);
    }
    __syncthreads();
    if (tid < 256) cur[tid] = CAP * tid + atomicAdd(&gcur[tid], cnt[tid]);
    __syncthreads();
    #pragma unroll
    for (int j = 0; j < 4; ++j) {
        int e = base + j * 1024 + tid;
        int d = __builtin_nontemporal_load(&dst[e]);
        int s = __builtin_nontemporal_load(&src[e]);
        int pos = atomicAdd(&cur[d >> 8], 1);
        pk[pos] = ((unsigned)s << 16) | (unsigned)d;
    }
}

__global__ __launch_bounds__(256) void k_boff(const int* __restrict__ gcur, int* __restrict__ boff,
                                              int* __restrict__ off) {
    __shared__ int sb[256];
    int tid = threadIdx.x;
    int v = gcur[tid] + 256;     // edges + one self loop per dst
    sb[tid] = v;
    __syncthreads();
    #pragma unroll
    for (int s = 1; s < 256; s <<= 1) {
        int t = (tid >= s) ? sb[tid - s] : 0;
        __syncthreads();
        sb[tid] += t;
        __syncthreads();
    }
    boff[tid] = sb[tid] - v;
    if (tid == 255) boff[256] = sb[255];
    if (tid == 0) off[N_NODES] = E_TOT;
}

__global__ __launch_bounds__(1024) void k_sortb(const unsigned* __restrict__ pk, const int* __restrict__ gcur,
                                                const int* __restrict__ boff, int* __restrict__ off,
                                                float* __restrict__ dis, ushort_t* __restrict__ ssort) {
    __shared__ int cnt[256];
    __shared__ int sb[256];
    __shared__ int cur[256];
    int b = blockIdx.x;
    int tid = threadIdx.x;
    int n = gcur[b];
    const unsigned* p = pk + (size_t)b * CAP;
    if (tid < 256) cnt[tid] = 0;
    __syncthreads();
    for (int i = tid; i < n; i += 1024) atomicAdd(&cnt[p[i] & 255u], 1);
    __syncthreads();
    if (tid < 256) sb[tid] = cnt[tid];
    __syncthreads();
    #pragma unroll
    for (int s = 1; s < 256; s <<= 1) {
        int t = (tid < 256 && tid >= s) ? sb[tid - s] : 0;
        __syncthreads();
        if (tid < 256) sb[tid] += t;
        __syncthreads();
    }
    if (tid < 256) {
        int deg = cnt[tid];
        int o = boff[b] + (sb[tid] - deg) + tid;
        int d = b * 256 + tid;
        off[d] = o;
        dis[d] = rsqrtf((float)(deg + 1));
        ssort[o + deg] = (ushort_t)d;
        cur[tid] = o;
    }
    __syncthreads();
    for (int i = tid; i < n; i += 1024) {
        unsigned v = p[i];
        int pos = atomicAdd(&cur[v & 255u], 1);
        ssort[pos] = (ushort_t)(v >> 16);
    }
}

// ---------------- fused: convx + W1 (bf16 hi/lo) + W2,W3 (fp16) fragment conversion ----------------

#define G1 (16 * 4 * 64)   // W1 128x256
#define G2 (8 * 8 * 64)    // W2 256x128
#define G3 (4 * 4 * 64)    // W3 128x64
#define NBX 8192           // convx blocks
#define NBW ((G1 + G2 + G3 + 255) / 256)

__device__ inline void convw_split(const float* W, int K, int N, short* Bh, short* Bl, int g) {
    int lane = g & 63;
    int kt = (g >> 6) % (K / 32);
    int nt = (g >> 6) / (K / 32);
    int n = nt * 16 + (lane & 15);
    int kbase = kt * 32 + (lane >> 4) * 8;
    #pragma unroll
    for (int j = 0; j < 8; ++j) {
        short h, l;
        split_bf16(W[(size_t)(kbase + j) * N + n], h, l);
        Bh[(size_t)g * 8 + j] = h;
        Bl[(size_t)g * 8 + j] = l;
    }
}

__device__ inline void convw_h(const float* W, int K, int N, _Float16* Bf, int g) {
    int lane = g & 63;
    int kt = (g >> 6) % (K / 32);
    int nt = (g >> 6) / (K / 32);
    int n = nt * 16 + (lane & 15);
    int kbase = kt * 32 + (lane >> 4) * 8;
    #pragma unroll
    for (int j = 0; j < 8; ++j)
        Bf[(size_t)g * 8 + j] = (_Float16)W[(size_t)(kbase + j) * N + n];
}

__global__ __launch_bounds__(256) void k_fused(
        const float* __restrict__ x, const float* __restrict__ dis, _Float16* __restrict__ xh,
        const float* __restrict__ W1, short* __restrict__ w1h, short* __restrict__ w1l,
        const float* __restrict__ W2, _Float16* __restrict__ w2f,
        const float* __restrict__ W3, _Float16* __restrict__ w3f) {
    int b = blockIdx.x;
    if (b < NBX) {
        int idx = (b * 256 + threadIdx.x) * 4;
        int row = idx >> 7;
        float d = dis[row];
        float4 v = *(const float4*)(x + idx);
        half4 o = {(_Float16)(d * v.x), (_Float16)(d * v.y), (_Float16)(d * v.z), (_Float16)(d * v.w)};
        *(half4*)(xh + idx) = o;
    } else {
        int g = (b - NBX) * 256 + threadIdx.x;
        if (g < G1)                 convw_split(W1, 128, 256, w1h, w1l, g);
        else if (g < G1 + G2)       convw_h(W2, 256, 128, w2f, g - G1);
        else if (g < G1 + G2 + G3)  convw_h(W3, 128, 64, w3f, g - G1 - G2);
    }
}

// ---------------- fused layers 1+2 GEMM, column-split: each wave owns a column slice ----------------

__global__ __launch_bounds__(256) void k_l12(const _Float16* __restrict__ A,
        const short* __restrict__ Bh, const short* __restrict__ Bl,
        const float* __restrict__ b1,
        const _Float16* __restrict__ w2f,
        const float* __restrict__ dis, _Float16* __restrict__ hh) {
    constexpr int LSTR = 280; // halves per row; dword stride 140 ≡ 12 (mod 32)
    __shared__ __align__(16) _Float16 xt[64][LSTR];
    __shared__ float red[2][4][64];

    int tid = threadIdx.x;
    int w = tid >> 6, lane = tid & 63;
    int quad = lane >> 4, li = lane & 15;
    size_t row0 = (size_t)blockIdx.x * 64;

    // ---- phase 1: x1^T cols [w*64, w*64+64), rows [row0, row0+64) ----
    floatx4 acc[4][4];   // [ntl][rt]
    #pragma unroll
    for (int ntl = 0; ntl < 4; ++ntl)
        #pragma unroll
        for (int rt = 0; rt < 4; ++rt) acc[ntl][rt] = (floatx4)0.0f;

    #pragma unroll
    for (int kt = 0; kt < 4; ++kt) {
        short8 afh[4], afl[4];
        #pragma unroll
        for (int rt = 0; rt < 4; ++rt) {
            half8 a8 = *(const half8*)(A + (row0 + rt * 16 + li) * 128 + kt * 32 + quad * 8);
            short ah[8], al[8];
            #pragma unroll
            for (int j = 0; j < 8; ++j) split_bf16((float)a8[j], ah[j], al[j]);
            afh[rt] = *(short8*)ah;
            afl[rt] = *(short8*)al;
        }
        #pragma unroll
        for (int ntl = 0; ntl < 4; ++ntl) {
            size_t bi = ((size_t)((w * 4 + ntl) * 4 + kt) * 64 + lane);
            short8 bfh = ((const short8*)Bh)[bi];
            short8 bfl = ((const short8*)Bl)[bi];
            #pragma unroll
            for (int rt = 0; rt < 4; ++rt) {
                acc[ntl][rt] = __builtin_amdgcn_mfma_f32_16x16x32_bf16(bfh, afh[rt], acc[ntl][rt], 0, 0, 0);
                acc[ntl][rt] = __builtin_amdgcn_mfma_f32_16x16x32_bf16(bfl, afh[rt], acc[ntl][rt], 0, 0, 0);
                acc[ntl][rt] = __builtin_amdgcn_mfma_f32_16x16x32_bf16(bfh, afl[rt], acc[ntl][rt], 0, 0, 0);
            }
        }
    }

    // ---- epilogue 1: bias + relu, cross-wave softmax, x1 -> LDS (fp16) ----
    float bb[4][4];
    #pragma unroll
    for (int ntl = 0; ntl < 4; ++ntl) {
        float4 bv = *(const float4*)(b1 + w * 64 + ntl * 16 + quad * 4);
        bb[ntl][0] = bv.x; bb[ntl][1] = bv.y; bb[ntl][2] = bv.z; bb[ntl][3] = bv.w;
    }
    float mr[4] = {0.f, 0.f, 0.f, 0.f};
    #pragma unroll
    for (int ntl = 0; ntl < 4; ++ntl)
        #pragma unroll
        for (int rt = 0; rt < 4; ++rt)
            #pragma unroll
            for (int r = 0; r < 4; ++r) {
                float v = fmaxf(acc[ntl][rt][r] + bb[ntl][r], 0.0f);
                acc[ntl][rt][r] = v;
                mr[rt] = fmaxf(mr[rt], v);
            }
    #pragma unroll
    for (int rt = 0; rt < 4; ++rt) {
        mr[rt] = fmaxf(mr[rt], __shfl_xor(mr[rt], 16, 64));
        mr[rt] = fmaxf(mr[rt], __shfl_xor(mr[rt], 32, 64));
    }
    {
        float wv = (quad == 0) ? mr[0] : (quad == 1) ? mr[1] : (quad == 2) ? mr[2] : mr[3];
        red[0][w][quad * 16 + li] = wv;
    }
    __syncthreads();
    float m[4];
    #pragma unroll
    for (int rt = 0; rt < 4; ++rt) {
        int idx = rt * 16 + li;
        m[rt] = fmaxf(fmaxf(red[0][0][idx], red[0][1][idx]), fmaxf(red[0][2][idx], red[0][3][idx]));
    }
    float sr[4] = {0.f, 0.f, 0.f, 0.f};
    #pragma unroll
    for (int ntl = 0; ntl < 4; ++ntl)
        #pragma unroll
        for (int rt = 0; rt < 4; ++rt)
            #pragma unroll
            for (int r = 0; r < 4; ++r) {
                float t = __expf(acc[ntl][rt][r] - m[rt]);
                acc[ntl][rt][r] = t;
                sr[rt] += t;
            }
    #pragma unroll
    for (int rt = 0; rt < 4; ++rt) {
        sr[rt] += __shfl_xor(sr[rt], 16, 64);
        sr[rt] += __shfl_xor(sr[rt], 32, 64);
    }
    {
        float sv = (quad == 0) ? sr[0] : (quad == 1) ? sr[1] : (quad == 2) ? sr[2] : sr[3];
        red[1][w][quad * 16 + li] = sv;
    }
    __syncthreads();
    float inv[4];
    #pragma unroll
    for (int rt = 0; rt < 4; ++rt) {
        int idx = rt * 16 + li;
        inv[rt] = 1.0f / (red[1][0][idx] + red[1][1][idx] + red[1][2][idx] + red[1][3][idx]);
    }
    #pragma unroll
    for (int ntl = 0; ntl < 4; ++ntl)
        #pragma unroll
        for (int rt = 0; rt < 4; ++rt) {
            half4 h4 = {(_Float16)(acc[ntl][rt][0] * inv[rt]), (_Float16)(acc[ntl][rt][1] * inv[rt]),
                        (_Float16)(acc[ntl][rt][2] * inv[rt]), (_Float16)(acc[ntl][rt][3] * inv[rt])};
            *(half4*)(&xt[rt * 16 + li][w * 64 + ntl * 16 + quad * 4]) = h4;
        }
    __syncthreads();

    // ---- phase 2: h2' cols [w*32, w*32+32), rows [row0, row0+64) ----
    floatx4 acc2[2][4];  // [ntl2][rt]
    #pragma unroll
    for (int ntl2 = 0; ntl2 < 2; ++ntl2)
        #pragma unroll
        for (int rt = 0; rt < 4; ++rt) acc2[ntl2][rt] = (floatx4)0.0f;

    #pragma unroll
    for (int kt = 0; kt < 8; ++kt) {
        half8 a8[4];
        #pragma unroll
        for (int rt = 0; rt < 4; ++rt)
            a8[rt] = *(const half8*)(&xt[rt * 16 + li][kt * 32 + quad * 8]);
        #pragma unroll
        for (int ntl2 = 0; ntl2 < 2; ++ntl2) {
            half8 bf = ((const half8*)w2f)[(size_t)((w * 2 + ntl2) * 8 + kt) * 64 + lane];
            #pragma unroll
            for (int rt = 0; rt < 4; ++rt)
                acc2[ntl2][rt] = __builtin_amdgcn_mfma_f32_16x16x32_f16(a8[rt], bf, acc2[ntl2][rt], 0, 0, 0);
        }
    }
    #pragma unroll
    for (int rt = 0; rt < 4; ++rt) {
        size_t rbase = row0 + rt * 16 + quad * 4;
        float4 d4 = *(const float4*)(dis + rbase);
        float dr[4] = {d4.x, d4.y, d4.z, d4.w};
        #pragma unroll
        for (int ntl2 = 0; ntl2 < 2; ++ntl2)
            #pragma unroll
            for (int r = 0; r < 4; ++r)
                hh[(rbase + r) * 128 + (w * 2 + ntl2) * 16 + li] = (_Float16)(acc2[ntl2][rt][r] * dr[r]);
    }
}

// ---------------- layer-3 GEMM with fused layer-2 activation prologue ----------------
// A-raw = segsum(h2') (fp16, raw). Prologue: x2 = softmax(relu(dis[row]*raw + b2)) computed
// per-lane over its 32 K-columns + cross-quad shfl reduce (full 128-col row). Same fp16
// quantization point as the old x2h round-trip. Then h3' = fp16(dis .* (x2 @ W3)).

__global__ __launch_bounds__(256) void k_mmh3(const _Float16* __restrict__ Araw,
                                              const _Float16* __restrict__ Bf,
                                              const float* __restrict__ dis, const float* __restrict__ b2,
                                              _Float16* __restrict__ Cout) {
    int tid = threadIdx.x;
    int wave = tid >> 6, lane = tid & 63;
    int quad = lane >> 4, col = lane & 15;
    size_t row0 = (size_t)blockIdx.x * 64;
    size_t arow = row0 + wave * 16 + col;
    const _Float16* ap = Araw + arow * 128 + quad * 8;

    half8 a8[4];
    #pragma unroll
    for (int kt = 0; kt < 4; ++kt) a8[kt] = *(const half8*)(ap + kt * 32);

    float dn = dis[arow];
    float v[4][8];
    float m = 0.0f;
    #pragma unroll
    for (int kt = 0; kt < 4; ++kt) {
        int c0 = kt * 32 + quad * 8;
        float4 bv0 = *(const float4*)(b2 + c0);
        float4 bv1 = *(const float4*)(b2 + c0 + 4);
        float bb[8] = {bv0.x, bv0.y, bv0.z, bv0.w, bv1.x, bv1.y, bv1.z, bv1.w};
        #pragma unroll
        for (int j = 0; j < 8; ++j) {
            float t = fmaxf(fmaf((float)a8[kt][j], dn, bb[j]), 0.0f);
            v[kt][j] = t;
            m = fmaxf(m, t);
        }
    }
    m = fmaxf(m, __shfl_xor(m, 16, 64));
    m = fmaxf(m, __shfl_xor(m, 32, 64));
    float sum = 0.0f;
    #pragma unroll
    for (int kt = 0; kt < 4; ++kt)
        #pragma unroll
        for (int j = 0; j < 8; ++j) {
            float t = __expf(v[kt][j] - m);
            v[kt][j] = t;
            sum += t;
        }
    sum += __shfl_xor(sum, 16, 64);
    sum += __shfl_xor(sum, 32, 64);
    float inv = 1.0f / sum;
    #pragma unroll
    for (int kt = 0; kt < 4; ++kt)
        #pragma unroll
        for (int j = 0; j < 8; ++j) a8[kt][j] = (_Float16)(v[kt][j] * inv);

    floatx4 acc[4];
    #pragma unroll
    for (int t = 0; t < 4; ++t) acc[t] = (floatx4)0.0f;
    #pragma unroll
    for (int kt = 0; kt < 4; ++kt)
        #pragma unroll
        for (int nt = 0; nt < 4; ++nt) {
            half8 bf = ((const half8*)Bf)[(size_t)(nt * 4 + kt) * 64 + lane];
            acc[nt] = __builtin_amdgcn_mfma_f32_16x16x32_f16(a8[kt], bf, acc[nt], 0, 0, 0);
        }

    size_t rbase = row0 + wave * 16 + quad * 4;
    float4 d4 = *(const float4*)(dis + rbase);
    float dr[4] = {d4.x, d4.y, d4.z, d4.w};
    #pragma unroll
    for (int nt = 0; nt < 4; ++nt)
        #pragma unroll
        for (int r = 0; r < 4; ++r)
            Cout[(rbase + r) * 64 + nt * 16 + col] = (_Float16)(acc[nt][r] * dr[r]);
}

// ---------------- column-slice aggregation (XCD-affine) ----------------
// Block b: column slice (b&7) of node chunk (b>>3). Round-robin blockIdx->XCD puts all
// blocks of slice s on XCD s -> that slice of the gather table (D/8 cols, <=2 MB) stays
// L2-resident; HBM fetch drops to ~table size. FACC=true: fp32 accumulate + dis scale
// (layer-1 pre-GEMM agg). FACC=false: pure fp16 accumulate, raw write (act applied by
// the consumer, which reads full rows). Summation structure identical to old k_aggq.

template <int D, bool FACC>
__global__ __launch_bounds__(256) void k_aggcs(const _Float16* __restrict__ h, const int* __restrict__ off,
                                               const ushort_t* __restrict__ ss, const float* __restrict__ dis,
                                               _Float16* __restrict__ out) {
    constexpr int W = D / 8;        // halves per slice (16 or 8)
    constexpr int LPN = W / 8;      // lanes per node (2 or 1)
    constexpr int NPW = 64 / LPN;   // nodes per wave (32 or 64)
    int slice = blockIdx.x & 7;
    int chunk = blockIdx.x >> 3;
    int lane = threadIdx.x & 63;
    int li   = (LPN == 1) ? 0 : (lane & (LPN - 1));
    int grp  = lane / LPN;
    int n = (chunk * 4 + (threadIdx.x >> 6)) * NPW + grp;
    int e0 = off[n], e1 = off[n + 1];

    const _Float16* hb = h + slice * W + li * 8;

    half8 hacc = {0, 0, 0, 0, 0, 0, 0, 0};
    half8 hacc2 = {0, 0, 0, 0, 0, 0, 0, 0};
    float facc[8];
    #pragma unroll
    for (int j = 0; j < 8; ++j) facc[j] = 0.0f;

    int e = e0;
    for (; e + 8 <= e1; e += 8) {
        int s0 = ss[e];
        int s1 = ss[e + 1];
        int s2 = ss[e + 2];
        int s3 = ss[e + 3];
        int s4 = ss[e + 4];
        int s5 = ss[e + 5];
        int s6 = ss[e + 6];
        int s7 = ss[e + 7];
        half8 v0 = *(const half8*)(hb + (size_t)s0 * D);
        half8 v1 = *(const half8*)(hb + (size_t)s1 * D);
        half8 v2 = *(const half8*)(hb + (size_t)s2 * D);
        half8 v3 = *(const half8*)(hb + (size_t)s3 * D);
        half8 v4 = *(const half8*)(hb + (size_t)s4 * D);
        half8 v5 = *(const half8*)(hb + (size_t)s5 * D);
        half8 v6 = *(const half8*)(hb + (size_t)s6 * D);
        half8 v7 = *(const half8*)(hb + (size_t)s7 * D);
        half8 p0 = (v0 + v1) + (v2 + v3);
        half8 p1 = (v4 + v5) + (v6 + v7);
        if constexpr (FACC) {
            #pragma unroll
            for (int j = 0; j < 8; ++j) facc[j] += (float)p0[j];
            #pragma unroll
            for (int j = 0; j < 8; ++j) facc[j] += (float)p1[j];
        } else {
            hacc  += p0;
            hacc2 += p1;
        }
    }
    for (; e + 4 <= e1; e += 4) {
        int s0 = ss[e];
        int s1 = ss[e + 1];
        int s2 = ss[e + 2];
        int s3 = ss[e + 3];
        half8 v0 = *(const half8*)(hb + (size_t)s0 * D);
        half8 v1 = *(const half8*)(hb + (size_t)s1 * D);
        half8 v2 = *(const half8*)(hb + (size_t)s2 * D);
        half8 v3 = *(const half8*)(hb + (size_t)s3 * D);
        half8 p = (v0 + v1) + (v2 + v3);
        if constexpr (FACC) {
            #pragma unroll
            for (int j = 0; j < 8; ++j) facc[j] += (float)p[j];
        } else {
            hacc += p;
        }
    }
    int rem = e1 - e;   // 0..3, uniform within the group
    if (rem > 0) {
        int s0 = ss[e];
        half8 p = *(const half8*)(hb + (size_t)s0 * D);
        if (rem > 1) {
            int s1 = ss[e + 1];
            p += *(const half8*)(hb + (size_t)s1 * D);
        }
        if (rem > 2) {
            int s2 = ss[e + 2];
            p += *(const half8*)(hb + (size_t)s2 * D);
        }
        if constexpr (FACC) {
            #pragma unroll
            for (int j = 0; j < 8; ++j) facc[j] += (float)p[j];
        } else {
            hacc += p;
        }
    }

    half8 o;
    if constexpr (FACC) {
        float dn = dis[n];
        #pragma unroll
        for (int j = 0; j < 8; ++j) o[j] = (_Float16)(facc[j] * dn);
    } else {
        hacc += hacc2;
        o = hacc;
    }
    *(half8*)(out + (size_t)n * D + slice * W + li * 8) = o;
}

// ---------------- final activation: out = softmax(relu(dis*raw + b3)), fp32 ----------------
// Arithmetic identical to the old k_agg64h epilogue (8 lanes per node, masks 4..1).

__global__ __launch_bounds__(256) void k_act64(const _Float16* __restrict__ raw, const float* __restrict__ dis,
                                               const float* __restrict__ b3, float* __restrict__ out) {
    int lane = threadIdx.x & 63;
    int li = lane & 7, grp = lane >> 3;
    int n = (blockIdx.x * 4 + (threadIdx.x >> 6)) * 8 + grp;
    half8 r = *(const half8*)(raw + (size_t)n * 64 + li * 8);
    float dn = dis[n];
    float facc[8];
    float m = 0.0f;
    #pragma unroll
    for (int j = 0; j < 8; ++j) {
        float vv = fmaxf(fmaf((float)r[j], dn, b3[li * 8 + j]), 0.0f);
        facc[j] = vv;
        m = fmaxf(m, vv);
    }
    #pragma unroll
    for (int mask = 4; mask > 0; mask >>= 1) m = fmaxf(m, __shfl_xor(m, mask, 64));
    float sum = 0.0f;
    #pragma unroll
    for (int j = 0; j < 8; ++j) {
        float t = __expf(facc[j] - m);
        facc[j] = t;
        sum += t;
    }
    #pragma unroll
    for (int mask = 4; mask > 0; mask >>= 1) sum += __shfl_xor(sum, mask, 64);
    float inv = 1.0f / sum;
    float* op = out + (size_t)n * 64 + li * 8;
    *(float4*)(op)     = make_float4(facc[0] * inv, facc[1] * inv, facc[2] * inv, facc[3] * inv);
    *(float4*)(op + 4) = make_float4(facc[4] * inv, facc[5] * inv, facc[6] * inv, facc[7] * inv);
}

// ---------------- launch ----------------

extern "C" void kernel_launch(void* const* d_in, const int* in_sizes, int n_in,
                              void* d_out, int out_size, void* d_ws, size_t ws_size,
                              hipStream_t stream) {
    const float* x  = (const float*)d_in[0];
    const int*   ei = (const int*)d_in[1];
    const float* W1 = (const float*)d_in[2];
    const float* b1 = (const float*)d_in[3];
    const float* W2 = (const float*)d_in[4];
    const float* b2 = (const float*)d_in[5];
    const float* W3 = (const float*)d_in[6];
    const float* b3 = (const float*)d_in[7];
    const int* srcE = ei;
    const int* dstE = ei + N_EDGES;

    char* p = (char*)d_ws;
    auto carve = [&](size_t bytes) {
        char* q = p;
        p += (bytes + 255) & ~(size_t)255;
        return q;
    };
    int*          gcur  = (int*)carve(sizeof(int) * 256);
    int*          boff  = (int*)carve(sizeof(int) * 257);
    int*          off   = (int*)carve(sizeof(int) * (N_NODES + 1));
    float*        dis   = (float*)carve(sizeof(float) * N_NODES);
    unsigned*     pk    = (unsigned*)carve(sizeof(unsigned) * 256 * CAP);
    ushort_t*     ssort = (ushort_t*)carve(sizeof(ushort_t) * E_TOT);
    short*        w1h   = (short*)carve(sizeof(short) * 128 * 256);
    short*        w1l   = (short*)carve(sizeof(short) * 128 * 256);
    _Float16*     w2f   = (_Float16*)carve(sizeof(_Float16) * 256 * 128);
    _Float16*     w3f   = (_Float16*)carve(sizeof(_Float16) * 128 * 64);
    _Float16*     xh    = (_Float16*)carve(sizeof(_Float16) * (size_t)N_NODES * 128);
    _Float16*     a0h   = (_Float16*)carve(sizeof(_Float16) * (size_t)N_NODES * 128);
    _Float16*     x2r   = (_Float16*)carve(sizeof(_Float16) * (size_t)N_NODES * 128);  // raw segsum(h2')
    _Float16*     hh    = (_Float16*)carve(sizeof(_Float16) * (size_t)N_NODES * 128);  // h2' then h3'
    _Float16*     o3r   = (_Float16*)carve(sizeof(_Float16) * (size_t)N_NODES * 64);   // raw segsum(h3')

    (void)hipMemsetAsync(gcur, 0, sizeof(int) * 256, stream);
    k_bucket<<<256, 1024, 0, stream>>>(srcE, dstE, gcur, pk);
    k_boff<<<1, 256, 0, stream>>>(gcur, boff, off);
    k_sortb<<<256, 1024, 0, stream>>>(pk, gcur, boff, off, dis, ssort);
    k_fused<<<NBX + NBW, 256, 0, stream>>>(x, dis, xh, W1, w1h, w1l, W2, w2f, W3, w3f);

    // layer 1 (agg-first, XCD column-slice): a0[n] = dis[n] * sum xh[src], fp16
    k_aggcs<128, true><<<(N_NODES / 128) * 8, 256, 0, stream>>>(xh, off, ssort, dis, a0h);
    // layers 1+2 fused GEMM (column-split): x1 = softmax(relu(a0@W1+b1)) [LDS], h2' = fp16(dis .* (x1@W2))
    k_l12<<<N_NODES / 64, 256, 0, stream>>>(a0h, w1h, w1l, b1, w2f, dis, hh);
    // layer 2 agg (raw, XCD column-slice): x2raw = segsum(h2'), fp16
    k_aggcs<128, false><<<(N_NODES / 128) * 8, 256, 0, stream>>>(hh, off, ssort, dis, x2r);
    // layer 3 GEMM with fused layer-2 activation: x2 = softmax(relu(dis*x2raw+b2)); h3' = fp16(dis .* (x2@W3))
    k_mmh3<<<N_NODES / 64, 256, 0, stream>>>(x2r, w3f, dis, b2, hh);
    // layer 3 agg (raw, XCD column-slice): o3raw = segsum(h3'), fp16
    k_aggcs<64, false><<<(N_NODES / 256) * 8, 256, 0, stream>>>(hh, off, ssort, dis, o3r);
    // final activation: out = softmax(relu(dis*o3raw + b3)), fp32
    k_act64<<<N_NODES / 32, 256, 0, stream>>>(o3r, dis, b3, (float*)d_out);
}

// Round 5
// 270.494 us; speedup vs baseline: 1.7774x; 1.7774x over previous
//
#include <hip/hip_runtime.h>
#include <cstdint>
#include <cstddef>

#define N_NODES 65536
#define N_EDGES 1048576
#define E_TOT   (N_EDGES + N_NODES)
#define CAP     5120   // bucket region capacity (mean 4096, +16 sigma)

using short8  = __attribute__((ext_vector_type(8))) short;
using floatx4 = __attribute__((ext_vector_type(4))) float;
using half8   = __attribute__((ext_vector_type(8))) _Float16;
using half4   = __attribute__((ext_vector_type(4))) _Float16;
typedef unsigned short ushort_t;

// split fp32 -> bf16 hi (RTN) + bf16 lo (trunc of residual)
__device__ inline void split_bf16(float a, short& hi, short& lo) {
    unsigned u  = __float_as_uint(a);
    unsigned hr = (u + 0x7fffu + ((u >> 16) & 1u)) >> 16;
    float    hf = __uint_as_float(hr << 16);
    hi = (short)hr;
    float    lf = a - hf;
    lo = (short)(__float_as_uint(lf) >> 16);
}

// ---------------- preprocessing: bucket counting sort ----------------

__global__ __launch_bounds__(1024) void k_bucket(const int* __restrict__ src, const int* __restrict__ dst,
                                                 int* __restrict__ gcur, unsigned* __restrict__ pk) {
    __shared__ int cnt[256];
    __shared__ int cur[256];
    int tid = threadIdx.x;
    if (tid < 256) cnt[tid] = 0;
    __syncthreads();
    int base = blockIdx.x * 4096;
    #pragma unroll
    for (int j = 0; j < 4; ++j) {
        int d = __builtin_nontemporal_load(&dst[base + j * 1024 + tid]);
        atomicAdd(&cnt[d >> 8], 1);
    }
    __syncthreads();
    if (tid < 256) cur[tid] = CAP * tid + atomicAdd(&gcur[tid], cnt[tid]);
    __syncthreads();
    #pragma unroll
    for (int j = 0; j < 4; ++j) {
        int e = base + j * 1024 + tid;
        int d = __builtin_nontemporal_load(&dst[e]);
        int s = __builtin_nontemporal_load(&src[e]);
        int pos = atomicAdd(&cur[d >> 8], 1);
        pk[pos] = ((unsigned)s << 16) | (unsigned)d;
    }
}

__global__ __launch_bounds__(256) void k_boff(const int* __restrict__ gcur, int* __restrict__ boff,
                                              int* __restrict__ off) {
    __shared__ int sb[256];
    int tid = threadIdx.x;
    int v = gcur[tid] + 256;     // edges + one self loop per dst
    sb[tid] = v;
    __syncthreads();
    #pragma unroll
    for (int s = 1; s < 256; s <<= 1) {
        int t = (tid >= s) ? sb[tid - s] : 0;
        __syncthreads();
        sb[tid] += t;
        __syncthreads();
    }
    boff[tid] = sb[tid] - v;
    if (tid == 255) boff[256] = sb[255];
    if (tid == 0) off[N_NODES] = E_TOT;
}

__global__ __launch_bounds__(1024) void k_sortb(const unsigned* __restrict__ pk, const int* __restrict__ gcur,
                                                const int* __restrict__ boff, int* __restrict__ off,
                                                float* __restrict__ dis, ushort_t* __restrict__ ssort) {
    __shared__ int cnt[256];
    __shared__ int sb[256];
    __shared__ int cur[256];
    int b = blockIdx.x;
    int tid = threadIdx.x;
    int n = gcur[b];
    const unsigned* p = pk + (size_t)b * CAP;
    if (tid < 256) cnt[tid] = 0;
    __syncthreads();
    for (int i = tid; i < n; i += 1024) atomicAdd(&cnt[p[i] & 255u], 1);
    __syncthreads();
    if (tid < 256) sb[tid] = cnt[tid];
    __syncthreads();
    #pragma unroll
    for (int s = 1; s < 256; s <<= 1) {
        int t = (tid < 256 && tid >= s) ? sb[tid - s] : 0;
        __syncthreads();
        if (tid < 256) sb[tid] += t;
        __syncthreads();
    }
    if (tid < 256) {
        int deg = cnt[tid];
        int o = boff[b] + (sb[tid] - deg) + tid;
        int d = b * 256 + tid;
        off[d] = o;
        dis[d] = rsqrtf((float)(deg + 1));
        ssort[o + deg] = (ushort_t)d;
        cur[tid] = o;
    }
    __syncthreads();
    for (int i = tid; i < n; i += 1024) {
        unsigned v = p[i];
        int pos = atomicAdd(&cur[v & 255u], 1);
        ssort[pos] = (ushort_t)(v >> 16);
    }
}

// ---------------- fused: convx + W1 (bf16 hi/lo) + W2,W3 (fp16) fragment conversion ----------------

#define G1 (16 * 4 * 64)   // W1 128x256
#define G2 (8 * 8 * 64)    // W2 256x128
#define G3 (4 * 4 * 64)    // W3 128x64
#define NBX 8192           // convx blocks
#define NBW ((G1 + G2 + G3 + 255) / 256)

__device__ inline void convw_split(const float* W, int K, int N, short* Bh, short* Bl, int g) {
    int lane = g & 63;
    int kt = (g >> 6) % (K / 32);
    int nt = (g >> 6) / (K / 32);
    int n = nt * 16 + (lane & 15);
    int kbase = kt * 32 + (lane >> 4) * 8;
    #pragma unroll
    for (int j = 0; j < 8; ++j) {
        short h, l;
        split_bf16(W[(size_t)(kbase + j) * N + n], h, l);
        Bh[(size_t)g * 8 + j] = h;
        Bl[(size_t)g * 8 + j] = l;
    }
}

__device__ inline void convw_h(const float* W, int K, int N, _Float16* Bf, int g) {
    int lane = g & 63;
    int kt = (g >> 6) % (K / 32);
    int nt = (g >> 6) / (K / 32);
    int n = nt * 16 + (lane & 15);
    int kbase = kt * 32 + (lane >> 4) * 8;
    #pragma unroll
    for (int j = 0; j < 8; ++j)
        Bf[(size_t)g * 8 + j] = (_Float16)W[(size_t)(kbase + j) * N + n];
}

__global__ __launch_bounds__(256) void k_fused(
        const float* __restrict__ x, const float* __restrict__ dis, _Float16* __restrict__ xh,
        const float* __restrict__ W1, short* __restrict__ w1h, short* __restrict__ w1l,
        const float* __restrict__ W2, _Float16* __restrict__ w2f,
        const float* __restrict__ W3, _Float16* __restrict__ w3f) {
    int b = blockIdx.x;
    if (b < NBX) {
        int idx = (b * 256 + threadIdx.x) * 4;
        int row = idx >> 7;
        float d = dis[row];
        float4 v = *(const float4*)(x + idx);
        half4 o = {(_Float16)(d * v.x), (_Float16)(d * v.y), (_Float16)(d * v.z), (_Float16)(d * v.w)};
        *(half4*)(xh + idx) = o;
    } else {
        int g = (b - NBX) * 256 + threadIdx.x;
        if (g < G1)                 convw_split(W1, 128, 256, w1h, w1l, g);
        else if (g < G1 + G2)       convw_h(W2, 256, 128, w2f, g - G1);
        else if (g < G1 + G2 + G3)  convw_h(W3, 128, 64, w3f, g - G1 - G2);
    }
}

// ---------------- fused layers 1+2 GEMM, 8-wave column-split, pre-split A ----------------
// Block = 64 rows, 8 waves (512 thr). Phase 1 (swapped MFMA, D = W1frag x a0frag = x1^T):
// wave w computes x1 cols [w*32, w*32+32) for ALL 64 rows. A comes PRE-SPLIT (bf16 hi/lo
// planes written by agg-1) -> no per-wave split_bf16 VALU work. Softmax: 2 cross-quad shfls
// for the wave partial, 8-entry LDS reduce. x1 (fp16, same quantization point) -> LDS tile
// (stride 280), phase 2: h2' cols [w*16, w*16+16) for all 64 rows.

__global__ __launch_bounds__(512) void k_l12(const short* __restrict__ Ahi, const short* __restrict__ Alo,
        const short* __restrict__ Bh, const short* __restrict__ Bl,
        const float* __restrict__ b1,
        const _Float16* __restrict__ w2f,
        const float* __restrict__ dis, _Float16* __restrict__ hh) {
    constexpr int LSTR = 280; // halves per row; dword stride 140 ≡ 12 (mod 32)
    __shared__ __align__(16) _Float16 xt[64][LSTR];
    __shared__ float red[2][8][64];

    int tid = threadIdx.x;
    int w = tid >> 6, lane = tid & 63;
    int quad = lane >> 4, li = lane & 15;
    size_t row0 = (size_t)blockIdx.x * 64;

    // ---- phase 1: x1^T cols [w*32, w*32+32), rows [row0, row0+64) ----
    floatx4 acc[2][4];   // [ntl][rt]
    #pragma unroll
    for (int ntl = 0; ntl < 2; ++ntl)
        #pragma unroll
        for (int rt = 0; rt < 4; ++rt) acc[ntl][rt] = (floatx4)0.0f;

    #pragma unroll
    for (int kt = 0; kt < 4; ++kt) {
        short8 afh[4], afl[4];
        #pragma unroll
        for (int rt = 0; rt < 4; ++rt) {
            size_t ao = (row0 + rt * 16 + li) * 128 + kt * 32 + quad * 8;
            afh[rt] = *(const short8*)(Ahi + ao);
            afl[rt] = *(const short8*)(Alo + ao);
        }
        #pragma unroll
        for (int ntl = 0; ntl < 2; ++ntl) {
            size_t bi = ((size_t)((w * 2 + ntl) * 4 + kt) * 64 + lane);
            short8 bfh = ((const short8*)Bh)[bi];
            short8 bfl = ((const short8*)Bl)[bi];
            #pragma unroll
            for (int rt = 0; rt < 4; ++rt) {
                acc[ntl][rt] = __builtin_amdgcn_mfma_f32_16x16x32_bf16(bfh, afh[rt], acc[ntl][rt], 0, 0, 0);
                acc[ntl][rt] = __builtin_amdgcn_mfma_f32_16x16x32_bf16(bfl, afh[rt], acc[ntl][rt], 0, 0, 0);
                acc[ntl][rt] = __builtin_amdgcn_mfma_f32_16x16x32_bf16(bfh, afl[rt], acc[ntl][rt], 0, 0, 0);
            }
        }
    }

    // ---- epilogue 1: bias + relu, cross-wave softmax, x1 -> LDS (fp16) ----
    float bb[2][4];
    #pragma unroll
    for (int ntl = 0; ntl < 2; ++ntl) {
        float4 bv = *(const float4*)(b1 + (w * 2 + ntl) * 16 + quad * 4);
        bb[ntl][0] = bv.x; bb[ntl][1] = bv.y; bb[ntl][2] = bv.z; bb[ntl][3] = bv.w;
    }
    float mr[4] = {0.f, 0.f, 0.f, 0.f};
    #pragma unroll
    for (int ntl = 0; ntl < 2; ++ntl)
        #pragma unroll
        for (int rt = 0; rt < 4; ++rt)
            #pragma unroll
            for (int r = 0; r < 4; ++r) {
                float v = fmaxf(acc[ntl][rt][r] + bb[ntl][r], 0.0f);
                acc[ntl][rt][r] = v;
                mr[rt] = fmaxf(mr[rt], v);
            }
    #pragma unroll
    for (int rt = 0; rt < 4; ++rt) {
        mr[rt] = fmaxf(mr[rt], __shfl_xor(mr[rt], 16, 64));
        mr[rt] = fmaxf(mr[rt], __shfl_xor(mr[rt], 32, 64));
    }
    {
        float wv = (quad == 0) ? mr[0] : (quad == 1) ? mr[1] : (quad == 2) ? mr[2] : mr[3];
        red[0][w][quad * 16 + li] = wv;
    }
    __syncthreads();
    float m[4];
    #pragma unroll
    for (int rt = 0; rt < 4; ++rt) {
        int idx = rt * 16 + li;
        float m01 = fmaxf(red[0][0][idx], red[0][1][idx]);
        float m23 = fmaxf(red[0][2][idx], red[0][3][idx]);
        float m45 = fmaxf(red[0][4][idx], red[0][5][idx]);
        float m67 = fmaxf(red[0][6][idx], red[0][7][idx]);
        m[rt] = fmaxf(fmaxf(m01, m23), fmaxf(m45, m67));
    }
    float sr[4] = {0.f, 0.f, 0.f, 0.f};
    #pragma unroll
    for (int ntl = 0; ntl < 2; ++ntl)
        #pragma unroll
        for (int rt = 0; rt < 4; ++rt)
            #pragma unroll
            for (int r = 0; r < 4; ++r) {
                float t = __expf(acc[ntl][rt][r] - m[rt]);
                acc[ntl][rt][r] = t;
                sr[rt] += t;
            }
    #pragma unroll
    for (int rt = 0; rt < 4; ++rt) {
        sr[rt] += __shfl_xor(sr[rt], 16, 64);
        sr[rt] += __shfl_xor(sr[rt], 32, 64);
    }
    {
        float sv = (quad == 0) ? sr[0] : (quad == 1) ? sr[1] : (quad == 2) ? sr[2] : sr[3];
        red[1][w][quad * 16 + li] = sv;
    }
    __syncthreads();
    float inv[4];
    #pragma unroll
    for (int rt = 0; rt < 4; ++rt) {
        int idx = rt * 16 + li;
        float s = ((red[1][0][idx] + red[1][1][idx]) + (red[1][2][idx] + red[1][3][idx]))
                + ((red[1][4][idx] + red[1][5][idx]) + (red[1][6][idx] + red[1][7][idx]));
        inv[rt] = 1.0f / s;
    }
    #pragma unroll
    for (int ntl = 0; ntl < 2; ++ntl)
        #pragma unroll
        for (int rt = 0; rt < 4; ++rt) {
            half4 h4 = {(_Float16)(acc[ntl][rt][0] * inv[rt]), (_Float16)(acc[ntl][rt][1] * inv[rt]),
                        (_Float16)(acc[ntl][rt][2] * inv[rt]), (_Float16)(acc[ntl][rt][3] * inv[rt])};
            *(half4*)(&xt[rt * 16 + li][(w * 2 + ntl) * 16 + quad * 4]) = h4;
        }
    __syncthreads();

    // ---- phase 2: h2' cols [w*16, w*16+16), rows [row0, row0+64) ----
    floatx4 acc2[4];  // [rt]
    #pragma unroll
    for (int rt = 0; rt < 4; ++rt) acc2[rt] = (floatx4)0.0f;

    #pragma unroll
    for (int kt = 0; kt < 8; ++kt) {
        half8 a8[4];
        #pragma unroll
        for (int rt = 0; rt < 4; ++rt)
            a8[rt] = *(const half8*)(&xt[rt * 16 + li][kt * 32 + quad * 8]);
        half8 bf = ((const half8*)w2f)[(size_t)(w * 8 + kt) * 64 + lane];
        #pragma unroll
        for (int rt = 0; rt < 4; ++rt)
            acc2[rt] = __builtin_amdgcn_mfma_f32_16x16x32_f16(a8[rt], bf, acc2[rt], 0, 0, 0);
    }
    #pragma unroll
    for (int rt = 0; rt < 4; ++rt) {
        size_t rbase = row0 + rt * 16 + quad * 4;
        float4 d4 = *(const float4*)(dis + rbase);
        float dr[4] = {d4.x, d4.y, d4.z, d4.w};
        #pragma unroll
        for (int r = 0; r < 4; ++r)
            hh[(rbase + r) * 128 + w * 16 + li] = (_Float16)(acc2[rt][r] * dr[r]);
    }
}

// ---------------- GEMM, fp16 path (layer 3): single f16 MFMA, no LDS, no barriers ----------------

template <int K, int N>
__global__ __launch_bounds__(256) void k_mmh(const _Float16* __restrict__ A,
                                             const _Float16* __restrict__ Bf,
                                             const float* __restrict__ dis, _Float16* __restrict__ Cout) {
    constexpr int NT = N / 16;
    constexpr int KT = K / 32;
    int tid = threadIdx.x;
    int wave = tid >> 6, lane = tid & 63;
    int quad = lane >> 4, col = lane & 15;
    size_t row0 = (size_t)blockIdx.x * 64;
    const _Float16* ap = A + (row0 + wave * 16 + col) * K + quad * 8;

    floatx4 acc[NT];
    #pragma unroll
    for (int t = 0; t < NT; ++t) acc[t] = (floatx4)0.0f;

    for (int kt = 0; kt < KT; ++kt) {
        half8 a8 = *(const half8*)(ap + kt * 32);
        #pragma unroll
        for (int nt = 0; nt < NT; ++nt) {
            half8 bf = ((const half8*)Bf)[(size_t)(nt * KT + kt) * 64 + lane];
            acc[nt] = __builtin_amdgcn_mfma_f32_16x16x32_f16(a8, bf, acc[nt], 0, 0, 0);
        }
    }

    size_t rbase = row0 + wave * 16 + quad * 4;
    float4 d4 = *(const float4*)(dis + rbase);
    float dr[4] = {d4.x, d4.y, d4.z, d4.w};
    #pragma unroll
    for (int nt = 0; nt < NT; ++nt)
        #pragma unroll
        for (int r = 0; r < 4; ++r)
            Cout[(rbase + r) * N + nt * 16 + col] = (_Float16)(acc[nt][r] * dr[r]);
}

// ---------------- aggregation: LPN lanes own one node end-to-end ----------------
// 8-edge unroll, dual fp16 chains -> 8 row-gathers in flight per group.
// OM=0: fp32 accumulate, dis-scale, write split-bf16 hi/lo planes (feeds k_l12 phase 1).
// OM=1: fp16 accumulate, act epilogue, fp16 out. OM=2: fp16 accumulate, act, fp32 out.

template <int LPN, int OM, typename OutT>
__global__ __launch_bounds__(256) void k_aggq(const _Float16* __restrict__ h, const int* __restrict__ off,
                                              const ushort_t* __restrict__ ss, const float* __restrict__ dis,
                                              const float* __restrict__ bias, OutT* __restrict__ out,
                                              short* __restrict__ oh, short* __restrict__ ol) {
    constexpr int D = LPN * 8;
    constexpr int NPW = 64 / LPN;
    int lane = threadIdx.x & 63;
    int grp  = lane / LPN;
    int li   = lane & (LPN - 1);
    int c0   = li * 8;
    int n = (blockIdx.x * 4 + (threadIdx.x >> 6)) * NPW + grp;
    int e0 = off[n], e1 = off[n + 1];

    const _Float16* hb = h + c0;

    half8 hacc = {0, 0, 0, 0, 0, 0, 0, 0};
    half8 hacc2 = {0, 0, 0, 0, 0, 0, 0, 0};
    float facc[8];
    #pragma unroll
    for (int j = 0; j < 8; ++j) facc[j] = 0.0f;

    int e = e0;
    for (; e + 8 <= e1; e += 8) {
        int s0 = ss[e];
        int s1 = ss[e + 1];
        int s2 = ss[e + 2];
        int s3 = ss[e + 3];
        int s4 = ss[e + 4];
        int s5 = ss[e + 5];
        int s6 = ss[e + 6];
        int s7 = ss[e + 7];
        half8 v0 = *(const half8*)(hb + (size_t)s0 * D);
        half8 v1 = *(const half8*)(hb + (size_t)s1 * D);
        half8 v2 = *(const half8*)(hb + (size_t)s2 * D);
        half8 v3 = *(const half8*)(hb + (size_t)s3 * D);
        half8 v4 = *(const half8*)(hb + (size_t)s4 * D);
        half8 v5 = *(const half8*)(hb + (size_t)s5 * D);
        half8 v6 = *(const half8*)(hb + (size_t)s6 * D);
        half8 v7 = *(const half8*)(hb + (size_t)s7 * D);
        half8 p0 = (v0 + v1) + (v2 + v3);
        half8 p1 = (v4 + v5) + (v6 + v7);
        if constexpr (OM != 0) {
            hacc  += p0;
            hacc2 += p1;
        } else {
            #pragma unroll
            for (int j = 0; j < 8; ++j) facc[j] += (float)p0[j];
            #pragma unroll
            for (int j = 0; j < 8; ++j) facc[j] += (float)p1[j];
        }
    }
    for (; e + 4 <= e1; e += 4) {
        int s0 = ss[e];
        int s1 = ss[e + 1];
        int s2 = ss[e + 2];
        int s3 = ss[e + 3];
        half8 v0 = *(const half8*)(hb + (size_t)s0 * D);
        half8 v1 = *(const half8*)(hb + (size_t)s1 * D);
        half8 v2 = *(const half8*)(hb + (size_t)s2 * D);
        half8 v3 = *(const half8*)(hb + (size_t)s3 * D);
        half8 p = (v0 + v1) + (v2 + v3);
        if constexpr (OM != 0) {
            hacc += p;
        } else {
            #pragma unroll
            for (int j = 0; j < 8; ++j) facc[j] += (float)p[j];
        }
    }
    int rem = e1 - e;   // 0..3, uniform within the group
    if (rem > 0) {
        int s0 = ss[e];
        half8 p = *(const half8*)(hb + (size_t)s0 * D);
        if (rem > 1) {
            int s1 = ss[e + 1];
            p += *(const half8*)(hb + (size_t)s1 * D);
        }
        if (rem > 2) {
            int s2 = ss[e + 2];
            p += *(const half8*)(hb + (size_t)s2 * D);
        }
        if constexpr (OM != 0) {
            hacc += p;
        } else {
            #pragma unroll
            for (int j = 0; j < 8; ++j) facc[j] += (float)p[j];
        }
    }
    if constexpr (OM != 0) {
        hacc += hacc2;
        #pragma unroll
        for (int j = 0; j < 8; ++j) facc[j] = (float)hacc[j];
    }

    float dn = dis[n];
    if constexpr (OM == 0) {
        short hi[8], lo[8];
        #pragma unroll
        for (int j = 0; j < 8; ++j) split_bf16(facc[j] * dn, hi[j], lo[j]);
        *(short8*)(oh + (size_t)n * D + c0) = *(short8*)hi;
        *(short8*)(ol + (size_t)n * D + c0) = *(short8*)lo;
        return;
    }

    float m = 0.0f;
    #pragma unroll
    for (int j = 0; j < 8; ++j) {
        float v = fmaxf(fmaf(facc[j], dn, bias[c0 + j]), 0.0f);
        facc[j] = v;
        m = fmaxf(m, v);
    }
    #pragma unroll
    for (int mask = LPN / 2; mask > 0; mask >>= 1) m = fmaxf(m, __shfl_xor(m, mask, 64));
    float sum = 0.0f;
    #pragma unroll
    for (int j = 0; j < 8; ++j) {
        float t = __expf(facc[j] - m);
        facc[j] = t;
        sum += t;
    }
    #pragma unroll
    for (int mask = LPN / 2; mask > 0; mask >>= 1) sum += __shfl_xor(sum, mask, 64);
    float inv = 1.0f / sum;
    #pragma unroll
    for (int j = 0; j < 8; ++j) facc[j] *= inv;

    if constexpr (sizeof(OutT) == 2) {
        half8 o;
        #pragma unroll
        for (int j = 0; j < 8; ++j) o[j] = (_Float16)facc[j];
        *(half8*)((_Float16*)out + (size_t)n * D + c0) = o;
    } else {
        float* op = (float*)out + (size_t)n * D + c0;
        *(float4*)(op)     = make_float4(facc[0], facc[1], facc[2], facc[3]);
        *(float4*)(op + 4) = make_float4(facc[4], facc[5], facc[6], facc[7]);
    }
}

// ---------------- launch ----------------

extern "C" void kernel_launch(void* const* d_in, const int* in_sizes, int n_in,
                              void* d_out, int out_size, void* d_ws, size_t ws_size,
                              hipStream_t stream) {
    const float* x  = (const float*)d_in[0];
    const int*   ei = (const int*)d_in[1];
    const float* W1 = (const float*)d_in[2];
    const float* b1 = (const float*)d_in[3];
    const float* W2 = (const float*)d_in[4];
    const float* b2 = (const float*)d_in[5];
    const float* W3 = (const float*)d_in[6];
    const float* b3 = (const float*)d_in[7];
    const int* srcE = ei;
    const int* dstE = ei + N_EDGES;

    char* p = (char*)d_ws;
    auto carve = [&](size_t bytes) {
        char* q = p;
        p += (bytes + 255) & ~(size_t)255;
        return q;
    };
    int*          gcur  = (int*)carve(sizeof(int) * 256);
    int*          boff  = (int*)carve(sizeof(int) * 257);
    int*          off   = (int*)carve(sizeof(int) * (N_NODES + 1));
    float*        dis   = (float*)carve(sizeof(float) * N_NODES);
    unsigned*     pk    = (unsigned*)carve(sizeof(unsigned) * 256 * CAP);
    ushort_t*     ssort = (ushort_t*)carve(sizeof(ushort_t) * E_TOT);
    short*        w1h   = (short*)carve(sizeof(short) * 128 * 256);
    short*        w1l   = (short*)carve(sizeof(short) * 128 * 256);
    _Float16*     w2f   = (_Float16*)carve(sizeof(_Float16) * 256 * 128);
    _Float16*     w3f   = (_Float16*)carve(sizeof(_Float16) * 128 * 64);
    _Float16*     xh    = (_Float16*)carve(sizeof(_Float16) * (size_t)N_NODES * 128);
    short*        a0hi  = (short*)carve(sizeof(short) * (size_t)N_NODES * 128);
    short*        a0lo  = (short*)carve(sizeof(short) * (size_t)N_NODES * 128);
    _Float16*     x2h   = (_Float16*)carve(sizeof(_Float16) * (size_t)N_NODES * 128);
    _Float16*     hh    = (_Float16*)carve(sizeof(_Float16) * (size_t)N_NODES * 128);  // h2' then h3'

    (void)hipMemsetAsync(gcur, 0, sizeof(int) * 256, stream);
    k_bucket<<<256, 1024, 0, stream>>>(srcE, dstE, gcur, pk);
    k_boff<<<1, 256, 0, stream>>>(gcur, boff, off);
    k_sortb<<<256, 1024, 0, stream>>>(pk, gcur, boff, off, dis, ssort);
    k_fused<<<NBX + NBW, 256, 0, stream>>>(x, dis, xh, W1, w1h, w1l, W2, w2f, W3, w3f);

    // layer 1 (agg-first): a0 = dis[n] * sum xh[src] -> split-bf16 hi/lo planes
    k_aggq<16, 0, _Float16><<<N_NODES / 16, 256, 0, stream>>>(xh, off, ssort, dis, nullptr,
                                                              (_Float16*)nullptr, a0hi, a0lo);
    // layers 1+2 fused GEMM (8-wave col-split): x1 = softmax(relu(a0@W1+b1)) [LDS], h2' = fp16(dis .* (x1@W2))
    k_l12<<<N_NODES / 64, 512, 0, stream>>>(a0hi, a0lo, w1h, w1l, b1, w2f, dis, hh);
    // layer 2 agg: x2 = softmax(relu(dis[n]*segsum(h2') + b2))
    k_aggq<16, 1, _Float16><<<N_NODES / 16, 256, 0, stream>>>(hh, off, ssort, dis, b2, x2h, nullptr, nullptr);
    // layer 3: h3' = fp16(dis .* (x2@W3)); out = softmax(relu(dis[n]*segsum(h3') + b3))
    k_mmh<128, 64><<<N_NODES / 64, 256, 0, stream>>>(x2h, w3f, dis, hh);
    k_aggq<8, 2, float><<<N_NODES / 32, 256, 0, stream>>>(hh, off, ssort, dis, b3, (float*)d_out, nullptr, nullptr);
}

// Round 6
// 248.436 us; speedup vs baseline: 1.9352x; 1.0888x over previous
//
#include <hip/hip_runtime.h>
#include <cstdint>
#include <cstddef>

#define N_NODES 65536
#define N_EDGES 1048576
#define E_TOT   (N_EDGES + N_NODES)
#define CAP     5120   // bucket region capacity (mean 4096, +16 sigma)

using short8  = __attribute__((ext_vector_type(8))) short;
using floatx4 = __attribute__((ext_vector_type(4))) float;
using half8   = __attribute__((ext_vector_type(8))) _Float16;
using half4   = __attribute__((ext_vector_type(4))) _Float16;
typedef unsigned short ushort_t;

// split fp32 -> bf16 hi (RTN) + bf16 lo (trunc of residual)
__device__ inline void split_bf16(float a, short& hi, short& lo) {
    unsigned u  = __float_as_uint(a);
    unsigned hr = (u + 0x7fffu + ((u >> 16) & 1u)) >> 16;
    float    hf = __uint_as_float(hr << 16);
    hi = (short)hr;
    float    lf = a - hf;
    lo = (short)(__float_as_uint(lf) >> 16);
}

// ---------------- preprocessing: bucket counting sort ----------------

__global__ __launch_bounds__(1024) void k_bucket(const int* __restrict__ src, const int* __restrict__ dst,
                                                 int* __restrict__ gcur, unsigned* __restrict__ pk) {
    __shared__ int cnt[256];
    __shared__ int cur[256];
    int tid = threadIdx.x;
    if (tid < 256) cnt[tid] = 0;
    __syncthreads();
    int base = blockIdx.x * 4096;
    #pragma unroll
    for (int j = 0; j < 4; ++j) {
        int d = __builtin_nontemporal_load(&dst[base + j * 1024 + tid]);
        atomicAdd(&cnt[d >> 8], 1);
    }
    __syncthreads();
    if (tid < 256) cur[tid] = CAP * tid + atomicAdd(&gcur[tid], cnt[tid]);
    __syncthreads();
    #pragma unroll
    for (int j = 0; j < 4; ++j) {
        int e = base + j * 1024 + tid;
        int d = __builtin_nontemporal_load(&dst[e]);
        int s = __builtin_nontemporal_load(&src[e]);
        int pos = atomicAdd(&cur[d >> 8], 1);
        pk[pos] = ((unsigned)s << 16) | (unsigned)d;
    }
}

__global__ __launch_bounds__(256) void k_boff(const int* __restrict__ gcur, int* __restrict__ boff,
                                              int* __restrict__ off) {
    __shared__ int sb[256];
    int tid = threadIdx.x;
    int v = gcur[tid] + 256;     // edges + one self loop per dst
    sb[tid] = v;
    __syncthreads();
    #pragma unroll
    for (int s = 1; s < 256; s <<= 1) {
        int t = (tid >= s) ? sb[tid - s] : 0;
        __syncthreads();
        sb[tid] += t;
        __syncthreads();
    }
    boff[tid] = sb[tid] - v;
    if (tid == 255) boff[256] = sb[255];
    if (tid == 0) off[N_NODES] = E_TOT;
}

__global__ __launch_bounds__(1024) void k_sortb(const unsigned* __restrict__ pk, const int* __restrict__ gcur,
                                                const int* __restrict__ boff, int* __restrict__ off,
                                                float* __restrict__ dis, ushort_t* __restrict__ ssort) {
    __shared__ int cnt[256];
    __shared__ int sb[256];
    __shared__ int cur[256];
    int b = blockIdx.x;
    int tid = threadIdx.x;
    int n = gcur[b];
    const unsigned* p = pk + (size_t)b * CAP;
    if (tid < 256) cnt[tid] = 0;
    __syncthreads();
    for (int i = tid; i < n; i += 1024) atomicAdd(&cnt[p[i] & 255u], 1);
    __syncthreads();
    if (tid < 256) sb[tid] = cnt[tid];
    __syncthreads();
    #pragma unroll
    for (int s = 1; s < 256; s <<= 1) {
        int t = (tid < 256 && tid >= s) ? sb[tid - s] : 0;
        __syncthreads();
        if (tid < 256) sb[tid] += t;
        __syncthreads();
    }
    if (tid < 256) {
        int deg = cnt[tid];
        int o = boff[b] + (sb[tid] - deg) + tid;
        int d = b * 256 + tid;
        off[d] = o;
        dis[d] = rsqrtf((float)(deg + 1));
        ssort[o + deg] = (ushort_t)d;
        cur[tid] = o;
    }
    __syncthreads();
    for (int i = tid; i < n; i += 1024) {
        unsigned v = p[i];
        int pos = atomicAdd(&cur[v & 255u], 1);
        ssort[pos] = (ushort_t)(v >> 16);
    }
}

// ---------------- fused: convx + W1 (bf16 hi/lo) + W2,W3 (fp16) fragment conversion ----------------

#define G1 (16 * 4 * 64)   // W1 128x256
#define G2 (8 * 8 * 64)    // W2 256x128
#define G3 (4 * 4 * 64)    // W3 128x64
#define NBX 8192           // convx blocks
#define NBW ((G1 + G2 + G3 + 255) / 256)

__device__ inline void convw_split(const float* W, int K, int N, short* Bh, short* Bl, int g) {
    int lane = g & 63;
    int kt = (g >> 6) % (K / 32);
    int nt = (g >> 6) / (K / 32);
    int n = nt * 16 + (lane & 15);
    int kbase = kt * 32 + (lane >> 4) * 8;
    #pragma unroll
    for (int j = 0; j < 8; ++j) {
        short h, l;
        split_bf16(W[(size_t)(kbase + j) * N + n], h, l);
        Bh[(size_t)g * 8 + j] = h;
        Bl[(size_t)g * 8 + j] = l;
    }
}

__device__ inline void convw_h(const float* W, int K, int N, _Float16* Bf, int g) {
    int lane = g & 63;
    int kt = (g >> 6) % (K / 32);
    int nt = (g >> 6) / (K / 32);
    int n = nt * 16 + (lane & 15);
    int kbase = kt * 32 + (lane >> 4) * 8;
    #pragma unroll
    for (int j = 0; j < 8; ++j)
        Bf[(size_t)g * 8 + j] = (_Float16)W[(size_t)(kbase + j) * N + n];
}

__global__ __launch_bounds__(256) void k_fused(
        const float* __restrict__ x, const float* __restrict__ dis, _Float16* __restrict__ xh,
        const float* __restrict__ W1, short* __restrict__ w1h, short* __restrict__ w1l,
        const float* __restrict__ W2, _Float16* __restrict__ w2f,
        const float* __restrict__ W3, _Float16* __restrict__ w3f) {
    int b = blockIdx.x;
    if (b < NBX) {
        int idx = (b * 256 + threadIdx.x) * 4;
        int row = idx >> 7;
        float d = dis[row];
        float4 v = *(const float4*)(x + idx);
        half4 o = {(_Float16)(d * v.x), (_Float16)(d * v.y), (_Float16)(d * v.z), (_Float16)(d * v.w)};
        *(half4*)(xh + idx) = o;
    } else {
        int g = (b - NBX) * 256 + threadIdx.x;
        if (g < G1)                 convw_split(W1, 128, 256, w1h, w1l, g);
        else if (g < G1 + G2)       convw_h(W2, 256, 128, w2f, g - G1);
        else if (g < G1 + G2 + G3)  convw_h(W3, 128, 64, w3f, g - G1 - G2);
    }
}

// ---------------- fused layers 1+2 GEMM, 4-wave column-split, LDS-staged A ----------------
// Block = 64 rows, 4 waves. STAGE: the fp16 A tile (16 KB) is loaded once, split_bf16 ONCE
// (32 splits/thread vs 128/lane in-loop), stored as hi/lo planes in LDS (rows padded to 136
// halves -> 2-way bank aliasing only). Phase 1 (swapped MFMA, D = W1frag x a0frag = x1^T):
// wave w computes x1 cols [w*64, w*64+64) for ALL 64 rows; A-fragments come from LDS.
// Softmax cross-wave (2 shfls + 4-entry LDS reduce). The A planes are dead after phase 1 and
// UNION with the x1 tile (35.8 KB peak). Phase 2: h2' cols [w*32,+32) for all 64 rows.
// Numerics identical to the round-3 kernel (same quantization chain).

__global__ __launch_bounds__(256) void k_l12(const _Float16* __restrict__ A,
        const short* __restrict__ Bh, const short* __restrict__ Bl,
        const float* __restrict__ b1,
        const _Float16* __restrict__ w2f,
        const float* __restrict__ dis, _Float16* __restrict__ hh) {
    constexpr int LSTR = 280; // x1 tile: halves per row; dword stride 140 ≡ 12 (mod 32)
    constexpr int ASTR = 136; // A planes: halves per row; dword stride 68 ≡ 4 (mod 32)
    __shared__ __align__(16) char smem[64 * LSTR * 2];   // 35840 B, unioned A-planes / x1
    __shared__ float red[2][4][64];
    short (*Ah)[ASTR] = (short(*)[ASTR])smem;                      // 17408 B
    short (*Al)[ASTR] = (short(*)[ASTR])(smem + 64 * ASTR * 2);    // 17408 B (total 34816)
    _Float16 (*xt)[LSTR] = (_Float16(*)[LSTR])smem;

    int tid = threadIdx.x;
    int w = tid >> 6, lane = tid & 63;
    int quad = lane >> 4, li = lane & 15;
    size_t row0 = (size_t)blockIdx.x * 64;

    // ---- stage: A (fp16) -> split-bf16 hi/lo planes in LDS, once per block ----
    {
        int r = tid >> 2, c0 = (tid & 3) * 32;
        const _Float16* ap = A + (row0 + r) * 128 + c0;
        #pragma unroll
        for (int j = 0; j < 4; ++j) {
            half8 a8 = *(const half8*)(ap + j * 8);
            short hi[8], lo[8];
            #pragma unroll
            for (int q = 0; q < 8; ++q) split_bf16((float)a8[q], hi[q], lo[q]);
            *(short8*)(&Ah[r][c0 + j * 8]) = *(short8*)hi;
            *(short8*)(&Al[r][c0 + j * 8]) = *(short8*)lo;
        }
    }
    __syncthreads();

    // ---- phase 1: x1^T cols [w*64, w*64+64), rows [row0, row0+64) ----
    floatx4 acc[4][4];   // [ntl][rt]
    #pragma unroll
    for (int ntl = 0; ntl < 4; ++ntl)
        #pragma unroll
        for (int rt = 0; rt < 4; ++rt) acc[ntl][rt] = (floatx4)0.0f;

    #pragma unroll
    for (int kt = 0; kt < 4; ++kt) {
        short8 afh[4], afl[4];
        #pragma unroll
        for (int rt = 0; rt < 4; ++rt) {
            afh[rt] = *(const short8*)(&Ah[rt * 16 + li][kt * 32 + quad * 8]);
            afl[rt] = *(const short8*)(&Al[rt * 16 + li][kt * 32 + quad * 8]);
        }
        #pragma unroll
        for (int ntl = 0; ntl < 4; ++ntl) {
            size_t bi = ((size_t)((w * 4 + ntl) * 4 + kt) * 64 + lane);
            short8 bfh = ((const short8*)Bh)[bi];
            short8 bfl = ((const short8*)Bl)[bi];
            #pragma unroll
            for (int rt = 0; rt < 4; ++rt) {
                acc[ntl][rt] = __builtin_amdgcn_mfma_f32_16x16x32_bf16(bfh, afh[rt], acc[ntl][rt], 0, 0, 0);
                acc[ntl][rt] = __builtin_amdgcn_mfma_f32_16x16x32_bf16(bfl, afh[rt], acc[ntl][rt], 0, 0, 0);
                acc[ntl][rt] = __builtin_amdgcn_mfma_f32_16x16x32_bf16(bfh, afl[rt], acc[ntl][rt], 0, 0, 0);
            }
        }
    }

    // ---- epilogue 1: bias + relu, cross-wave softmax, x1 -> LDS (fp16) ----
    float bb[4][4];
    #pragma unroll
    for (int ntl = 0; ntl < 4; ++ntl) {
        float4 bv = *(const float4*)(b1 + w * 64 + ntl * 16 + quad * 4);
        bb[ntl][0] = bv.x; bb[ntl][1] = bv.y; bb[ntl][2] = bv.z; bb[ntl][3] = bv.w;
    }
    float mr[4] = {0.f, 0.f, 0.f, 0.f};
    #pragma unroll
    for (int ntl = 0; ntl < 4; ++ntl)
        #pragma unroll
        for (int rt = 0; rt < 4; ++rt)
            #pragma unroll
            for (int r = 0; r < 4; ++r) {
                float v = fmaxf(acc[ntl][rt][r] + bb[ntl][r], 0.0f);
                acc[ntl][rt][r] = v;
                mr[rt] = fmaxf(mr[rt], v);
            }
    #pragma unroll
    for (int rt = 0; rt < 4; ++rt) {
        mr[rt] = fmaxf(mr[rt], __shfl_xor(mr[rt], 16, 64));
        mr[rt] = fmaxf(mr[rt], __shfl_xor(mr[rt], 32, 64));
    }
    {
        float wv = (quad == 0) ? mr[0] : (quad == 1) ? mr[1] : (quad == 2) ? mr[2] : mr[3];
        red[0][w][quad * 16 + li] = wv;
    }
    __syncthreads();   // also: all waves are done reading A planes after this point
    float m[4];
    #pragma unroll
    for (int rt = 0; rt < 4; ++rt) {
        int idx = rt * 16 + li;
        m[rt] = fmaxf(fmaxf(red[0][0][idx], red[0][1][idx]), fmaxf(red[0][2][idx], red[0][3][idx]));
    }
    float sr[4] = {0.f, 0.f, 0.f, 0.f};
    #pragma unroll
    for (int ntl = 0; ntl < 4; ++ntl)
        #pragma unroll
        for (int rt = 0; rt < 4; ++rt)
            #pragma unroll
            for (int r = 0; r < 4; ++r) {
                float t = __expf(acc[ntl][rt][r] - m[rt]);
                acc[ntl][rt][r] = t;
                sr[rt] += t;
            }
    #pragma unroll
    for (int rt = 0; rt < 4; ++rt) {
        sr[rt] += __shfl_xor(sr[rt], 16, 64);
        sr[rt] += __shfl_xor(sr[rt], 32, 64);
    }
    {
        float sv = (quad == 0) ? sr[0] : (quad == 1) ? sr[1] : (quad == 2) ? sr[2] : sr[3];
        red[1][w][quad * 16 + li] = sv;
    }
    __syncthreads();
    float inv[4];
    #pragma unroll
    for (int rt = 0; rt < 4; ++rt) {
        int idx = rt * 16 + li;
        inv[rt] = 1.0f / (red[1][0][idx] + red[1][1][idx] + red[1][2][idx] + red[1][3][idx]);
    }
    #pragma unroll
    for (int ntl = 0; ntl < 4; ++ntl)
        #pragma unroll
        for (int rt = 0; rt < 4; ++rt) {
            half4 h4 = {(_Float16)(acc[ntl][rt][0] * inv[rt]), (_Float16)(acc[ntl][rt][1] * inv[rt]),
                        (_Float16)(acc[ntl][rt][2] * inv[rt]), (_Float16)(acc[ntl][rt][3] * inv[rt])};
            *(half4*)(&xt[rt * 16 + li][w * 64 + ntl * 16 + quad * 4]) = h4;
        }
    __syncthreads();

    // ---- phase 2: h2' cols [w*32, w*32+32), rows [row0, row0+64) ----
    floatx4 acc2[2][4];  // [ntl2][rt]
    #pragma unroll
    for (int ntl2 = 0; ntl2 < 2; ++ntl2)
        #pragma unroll
        for (int rt = 0; rt < 4; ++rt) acc2[ntl2][rt] = (floatx4)0.0f;

    #pragma unroll
    for (int kt = 0; kt < 8; ++kt) {
        half8 a8[4];
        #pragma unroll
        for (int rt = 0; rt < 4; ++rt)
            a8[rt] = *(const half8*)(&xt[rt * 16 + li][kt * 32 + quad * 8]);
        #pragma unroll
        for (int ntl2 = 0; ntl2 < 2; ++ntl2) {
            half8 bf = ((const half8*)w2f)[(size_t)((w * 2 + ntl2) * 8 + kt) * 64 + lane];
            #pragma unroll
            for (int rt = 0; rt < 4; ++rt)
                acc2[ntl2][rt] = __builtin_amdgcn_mfma_f32_16x16x32_f16(a8[rt], bf, acc2[ntl2][rt], 0, 0, 0);
        }
    }
    #pragma unroll
    for (int rt = 0; rt < 4; ++rt) {
        size_t rbase = row0 + rt * 16 + quad * 4;
        float4 d4 = *(const float4*)(dis + rbase);
        float dr[4] = {d4.x, d4.y, d4.z, d4.w};
        #pragma unroll
        for (int ntl2 = 0; ntl2 < 2; ++ntl2)
            #pragma unroll
            for (int r = 0; r < 4; ++r)
                hh[(rbase + r) * 128 + (w * 2 + ntl2) * 16 + li] = (_Float16)(acc2[ntl2][rt][r] * dr[r]);
    }
}

// ---------------- GEMM, fp16 path (layer 3): single f16 MFMA, no LDS, no barriers ----------------

template <int K, int N>
__global__ __launch_bounds__(256) void k_mmh(const _Float16* __restrict__ A,
                                             const _Float16* __restrict__ Bf,
                                             const float* __restrict__ dis, _Float16* __restrict__ Cout) {
    constexpr int NT = N / 16;
    constexpr int KT = K / 32;
    int tid = threadIdx.x;
    int wave = tid >> 6, lane = tid & 63;
    int quad = lane >> 4, col = lane & 15;
    size_t row0 = (size_t)blockIdx.x * 64;
    const _Float16* ap = A + (row0 + wave * 16 + col) * K + quad * 8;

    floatx4 acc[NT];
    #pragma unroll
    for (int t = 0; t < NT; ++t) acc[t] = (floatx4)0.0f;

    for (int kt = 0; kt < KT; ++kt) {
        half8 a8 = *(const half8*)(ap + kt * 32);
        #pragma unroll
        for (int nt = 0; nt < NT; ++nt) {
            half8 bf = ((const half8*)Bf)[(size_t)(nt * KT + kt) * 64 + lane];
            acc[nt] = __builtin_amdgcn_mfma_f32_16x16x32_f16(a8, bf, acc[nt], 0, 0, 0);
        }
    }

    size_t rbase = row0 + wave * 16 + quad * 4;
    float4 d4 = *(const float4*)(dis + rbase);
    float dr[4] = {d4.x, d4.y, d4.z, d4.w};
    #pragma unroll
    for (int nt = 0; nt < NT; ++nt)
        #pragma unroll
        for (int r = 0; r < 4; ++r)
            Cout[(rbase + r) * N + nt * 16 + col] = (_Float16)(acc[nt][r] * dr[r]);
}

// ---------------- aggregation: LPN lanes own one node end-to-end ----------------
// 8-edge unroll with dual fp16 chains: 8 row-gathers in flight per group.

template <int LPN, bool ACT, typename OutT>
__global__ __launch_bounds__(256) void k_aggq(const _Float16* __restrict__ h, const int* __restrict__ off,
                                              const ushort_t* __restrict__ ss, const float* __restrict__ dis,
                                              const float* __restrict__ bias, OutT* __restrict__ out) {
    constexpr int D = LPN * 8;
    constexpr int NPW = 64 / LPN;
    int lane = threadIdx.x & 63;
    int grp  = lane / LPN;
    int li   = lane & (LPN - 1);
    int c0   = li * 8;
    int n = (blockIdx.x * 4 + (threadIdx.x >> 6)) * NPW + grp;
    int e0 = off[n], e1 = off[n + 1];

    const _Float16* hb = h + c0;

    half8 hacc = {0, 0, 0, 0, 0, 0, 0, 0};
    half8 hacc2 = {0, 0, 0, 0, 0, 0, 0, 0};
    float facc[8];
    #pragma unroll
    for (int j = 0; j < 8; ++j) facc[j] = 0.0f;

    int e = e0;
    for (; e + 8 <= e1; e += 8) {
        int s0 = ss[e];
        int s1 = ss[e + 1];
        int s2 = ss[e + 2];
        int s3 = ss[e + 3];
        int s4 = ss[e + 4];
        int s5 = ss[e + 5];
        int s6 = ss[e + 6];
        int s7 = ss[e + 7];
        half8 v0 = *(const half8*)(hb + (size_t)s0 * D);
        half8 v1 = *(const half8*)(hb + (size_t)s1 * D);
        half8 v2 = *(const half8*)(hb + (size_t)s2 * D);
        half8 v3 = *(const half8*)(hb + (size_t)s3 * D);
        half8 v4 = *(const half8*)(hb + (size_t)s4 * D);
        half8 v5 = *(const half8*)(hb + (size_t)s5 * D);
        half8 v6 = *(const half8*)(hb + (size_t)s6 * D);
        half8 v7 = *(const half8*)(hb + (size_t)s7 * D);
        half8 p0 = (v0 + v1) + (v2 + v3);
        half8 p1 = (v4 + v5) + (v6 + v7);
        if constexpr (ACT) {
            hacc  += p0;
            hacc2 += p1;
        } else {
            #pragma unroll
            for (int j = 0; j < 8; ++j) facc[j] += (float)p0[j];
            #pragma unroll
            for (int j = 0; j < 8; ++j) facc[j] += (float)p1[j];
        }
    }
    for (; e + 4 <= e1; e += 4) {
        int s0 = ss[e];
        int s1 = ss[e + 1];
        int s2 = ss[e + 2];
        int s3 = ss[e + 3];
        half8 v0 = *(const half8*)(hb + (size_t)s0 * D);
        half8 v1 = *(const half8*)(hb + (size_t)s1 * D);
        half8 v2 = *(const half8*)(hb + (size_t)s2 * D);
        half8 v3 = *(const half8*)(hb + (size_t)s3 * D);
        half8 p = (v0 + v1) + (v2 + v3);
        if constexpr (ACT) {
            hacc += p;
        } else {
            #pragma unroll
            for (int j = 0; j < 8; ++j) facc[j] += (float)p[j];
        }
    }
    int rem = e1 - e;   // 0..3, uniform within the group
    if (rem > 0) {
        int s0 = ss[e];
        half8 p = *(const half8*)(hb + (size_t)s0 * D);
        if (rem > 1) {
            int s1 = ss[e + 1];
            p += *(const half8*)(hb + (size_t)s1 * D);
        }
        if (rem > 2) {
            int s2 = ss[e + 2];
            p += *(const half8*)(hb + (size_t)s2 * D);
        }
        if constexpr (ACT) {
            hacc += p;
        } else {
            #pragma unroll
            for (int j = 0; j < 8; ++j) facc[j] += (float)p[j];
        }
    }
    if constexpr (ACT) {
        hacc += hacc2;
        #pragma unroll
        for (int j = 0; j < 8; ++j) facc[j] = (float)hacc[j];
    }

    float dn = dis[n];
    if constexpr (ACT) {
        float m = 0.0f;
        #pragma unroll
        for (int j = 0; j < 8; ++j) {
            float v = fmaxf(fmaf(facc[j], dn, bias[c0 + j]), 0.0f);
            facc[j] = v;
            m = fmaxf(m, v);
        }
        #pragma unroll
        for (int mask = LPN / 2; mask > 0; mask >>= 1) m = fmaxf(m, __shfl_xor(m, mask, 64));
        float sum = 0.0f;
        #pragma unroll
        for (int j = 0; j < 8; ++j) {
            float t = __expf(facc[j] - m);
            facc[j] = t;
            sum += t;
        }
        #pragma unroll
        for (int mask = LPN / 2; mask > 0; mask >>= 1) sum += __shfl_xor(sum, mask, 64);
        float inv = 1.0f / sum;
        #pragma unroll
        for (int j = 0; j < 8; ++j) facc[j] *= inv;
    } else {
        #pragma unroll
        for (int j = 0; j < 8; ++j) facc[j] *= dn;
    }

    if constexpr (sizeof(OutT) == 2) {
        half8 o;
        #pragma unroll
        for (int j = 0; j < 8; ++j) o[j] = (_Float16)facc[j];
        *(half8*)((_Float16*)out + (size_t)n * D + c0) = o;
    } else {
        float* op = (float*)out + (size_t)n * D + c0;
        *(float4*)(op)     = make_float4(facc[0], facc[1], facc[2], facc[3]);
        *(float4*)(op + 4) = make_float4(facc[4], facc[5], facc[6], facc[7]);
    }
}

// ---------------- launch ----------------

extern "C" void kernel_launch(void* const* d_in, const int* in_sizes, int n_in,
                              void* d_out, int out_size, void* d_ws, size_t ws_size,
                              hipStream_t stream) {
    const float* x  = (const float*)d_in[0];
    const int*   ei = (const int*)d_in[1];
    const float* W1 = (const float*)d_in[2];
    const float* b1 = (const float*)d_in[3];
    const float* W2 = (const float*)d_in[4];
    const float* b2 = (const float*)d_in[5];
    const float* W3 = (const float*)d_in[6];
    const float* b3 = (const float*)d_in[7];
    const int* srcE = ei;
    const int* dstE = ei + N_EDGES;

    char* p = (char*)d_ws;
    auto carve = [&](size_t bytes) {
        char* q = p;
        p += (bytes + 255) & ~(size_t)255;
        return q;
    };
    int*          gcur  = (int*)carve(sizeof(int) * 256);
    int*          boff  = (int*)carve(sizeof(int) * 257);
    int*          off   = (int*)carve(sizeof(int) * (N_NODES + 1));
    float*        dis   = (float*)carve(sizeof(float) * N_NODES);
    unsigned*     pk    = (unsigned*)carve(sizeof(unsigned) * 256 * CAP);
    ushort_t*     ssort = (ushort_t*)carve(sizeof(ushort_t) * E_TOT);
    short*        w1h   = (short*)carve(sizeof(short) * 128 * 256);
    short*        w1l   = (short*)carve(sizeof(short) * 128 * 256);
    _Float16*     w2f   = (_Float16*)carve(sizeof(_Float16) * 256 * 128);
    _Float16*     w3f   = (_Float16*)carve(sizeof(_Float16) * 128 * 64);
    _Float16*     xh    = (_Float16*)carve(sizeof(_Float16) * (size_t)N_NODES * 128);
    _Float16*     a0h   = (_Float16*)carve(sizeof(_Float16) * (size_t)N_NODES * 128);
    _Float16*     x2h   = (_Float16*)carve(sizeof(_Float16) * (size_t)N_NODES * 128);
    _Float16*     hh    = (_Float16*)carve(sizeof(_Float16) * (size_t)N_NODES * 128);  // h2' then h3'

    (void)hipMemsetAsync(gcur, 0, sizeof(int) * 256, stream);
    k_bucket<<<256, 1024, 0, stream>>>(srcE, dstE, gcur, pk);
    k_boff<<<1, 256, 0, stream>>>(gcur, boff, off);
    k_sortb<<<256, 1024, 0, stream>>>(pk, gcur, boff, off, dis, ssort);
    k_fused<<<NBX + NBW, 256, 0, stream>>>(x, dis, xh, W1, w1h, w1l, W2, w2f, W3, w3f);

    // layer 1 (agg-first): a0[n] = dis[n] * sum xh[src], fp16 (quarter-wave per node)
    k_aggq<16, false, _Float16><<<N_NODES / 16, 256, 0, stream>>>(xh, off, ssort, dis, nullptr, a0h);
    // layers 1+2 fused GEMM (col-split, LDS-staged A): x1 = softmax(relu(a0@W1+b1)) [LDS], h2' = fp16(dis .* (x1@W2))
    k_l12<<<N_NODES / 64, 256, 0, stream>>>(a0h, w1h, w1l, b1, w2f, dis, hh);
    // layer 2 agg: x2 = softmax(relu(dis[n]*segsum(h2') + b2))
    k_aggq<16, true, _Float16><<<N_NODES / 16, 256, 0, stream>>>(hh, off, ssort, dis, b2, x2h);
    // layer 3: h3' = fp16(dis .* (x2@W3)); out = softmax(relu(dis[n]*segsum(h3') + b3))
    k_mmh<128, 64><<<N_NODES / 64, 256, 0, stream>>>(x2h, w3f, dis, hh);
    k_aggq<8, true, float><<<N_NODES / 32, 256, 0, stream>>>(hh, off, ssort, dis, b3, (float*)d_out);
}